// Round 13
// baseline (35.031 us; speedup 1.0000x reference)
//
#include <hip/hip_runtime.h>

typedef float v2f __attribute__((ext_vector_type(2)));
typedef float v4f __attribute__((ext_vector_type(4)));

#define FEPS 1e-16f
#define LOG_2PI 1.8378770664093453f
#define DUMMYV -4.605170185988091f   /* -2*log(10) */
#define LOG2E 1.4426950408889634f
#define LN2 0.6931471805599453f

constexpr int B = 32, N = 1024, V = 512;
constexpr int ROWS_PER_BLOCK = 32;
constexpr int GRID_X = N / ROWS_PER_BLOCK;   // 32 -> 1024 blocks (proven best)

constexpr long long OFF_LOGPROB    = 0;
constexpr long long OFF_VOTEPRES   = 1;
constexpr long long OFF_WINNER     = OFF_VOTEPRES + (long long)B * V;
constexpr long long OFF_WINNERPRES = OFF_WINNER + (long long)B * N * 4;
constexpr long long OFF_ISFROM     = OFF_WINNERPRES + (long long)B * N;
constexpr long long OFF_MLOGITS    = OFF_ISFROM + (long long)B * N;
constexpr long long OFF_MLOGPROB   = OFF_MLOGITS + (long long)B * (V + 1);
constexpr long long OFF_ZW         = OFF_MLOGPROB + (long long)B * (V + 1);
constexpr long long OFF_ZWP        = OFF_ZW + (long long)B * N * 4;
constexpr long long OFF_PMP        = OFF_ZWP + (long long)B * N;
// Probs row byte base ≡ 4 (mod 16). Shift-3 ownership: element 3+4l is at
// byte 16+16l (16B aligned), element 259+4l at byte 1040+16l (aligned).

__device__ __forceinline__ float fexp2(float x) {
#if __has_builtin(__builtin_amdgcn_exp2f)
    return __builtin_amdgcn_exp2f(x);
#else
    return __expf(x * LN2);
#endif
}
__device__ __forceinline__ float frcp(float x) {
#if __has_builtin(__builtin_amdgcn_rcpf)
    return __builtin_amdgcn_rcpf(x);
#else
    return 1.0f / x;
#endif
}

template<int RN> __device__ __forceinline__ float dppRorF(float x) {
    return __int_as_float(__builtin_amdgcn_update_dpp(
        0, __float_as_int(x), 0x120 | RN, 0xF, 0xF, false));
}
template<int RN> __device__ __forceinline__ int dppRorI(int x) {
    return __builtin_amdgcn_update_dpp(0, x, 0x120 | RN, 0xF, 0xF, false);
}
// xor-16 butterfly step via ds_swizzle bitmode: offset = (16<<10)|0x1F
__device__ __forceinline__ float swz16F(float x) {
    return __int_as_float(__builtin_amdgcn_ds_swizzle(__float_as_int(x), 0x401F));
}
__device__ __forceinline__ int swz16I(int x) {
    return __builtin_amdgcn_ds_swizzle(x, 0x401F);
}

// xor-32 step: permlane32_swap (VALU pipe) if available, else shfl (LDS pipe)
#if __has_builtin(__builtin_amdgcn_permlane32_swap)
__device__ __forceinline__ float maxSwap32(float x) {
    auto r = __builtin_amdgcn_permlane32_swap(__float_as_uint(x), __float_as_uint(x), false, false);
    return fmaxf(__uint_as_float(r[0]), __uint_as_float(r[1]));
}
__device__ __forceinline__ float sumSwap32(float x) {
    auto r = __builtin_amdgcn_permlane32_swap(__float_as_uint(x), __float_as_uint(x), false, false);
    return __uint_as_float(r[0]) + __uint_as_float(r[1]);
}
__device__ __forceinline__ int minSwap32(int x) {
    auto r = __builtin_amdgcn_permlane32_swap((unsigned)x, (unsigned)x, false, false);
    int a = (int)r[0], b = (int)r[1];
    return a < b ? a : b;
}
#else
__device__ __forceinline__ float maxSwap32(float x) { return fmaxf(x, __shfl_xor(x, 32)); }
__device__ __forceinline__ float sumSwap32(float x) { return x + __shfl_xor(x, 32); }
__device__ __forceinline__ int   minSwap32(int x)   { int o = __shfl_xor(x, 32); return o < x ? o : x; }
#endif

__device__ __forceinline__ float waveMaxF(float m) {
    m = fmaxf(m, dppRorF<1>(m));
    m = fmaxf(m, dppRorF<2>(m));
    m = fmaxf(m, dppRorF<4>(m));
    m = fmaxf(m, dppRorF<8>(m));
    m = fmaxf(m, swz16F(m));
    return maxSwap32(m);
}
__device__ __forceinline__ float waveSumF(float s) {
    s += dppRorF<1>(s);
    s += dppRorF<2>(s);
    s += dppRorF<4>(s);
    s += dppRorF<8>(s);
    s += swz16F(s);
    return sumSwap32(s);
}
__device__ __forceinline__ int waveMinI(int v) {
    int o;
    o = dppRorI<1>(v); v = o < v ? o : v;
    o = dppRorI<2>(v); v = o < v ? o : v;
    o = dppRorI<4>(v); v = o < v ? o : v;
    o = dppRorI<8>(v); v = o < v ? o : v;
    o = swz16I(v);     v = o < v ? o : v;
    return minSwap32(v);
}

__global__ __launch_bounds__(256) void k_fused(const float* __restrict__ x,
                                               const float* __restrict__ votes,
                                               const float* __restrict__ scales,
                                               const float* __restrict__ vpp,
                                               const float* __restrict__ presence,
                                               const int* __restrict__ nvp,
                                               float* __restrict__ out,
                                               float* __restrict__ ws) {
    // Coeff arrays shifted by +1 slot so vote v lives at [v+1]:
    // group A base (3+4l)+1 = 4+4l  -> 16B-aligned ds_read_b128
    // group B base (259+4l)+1 = 260+4l -> 16B-aligned
    __shared__ float s_c2[513], s_hk[513], s_ax[513], s_ay[513], s_az[513], s_aw[513];
    __shared__ float s_m[4], s_s[4], s_part[4];

    const int b = blockIdx.y, t = threadIdx.x, w = t >> 6, lane = t & 63;
    const long long bV = (long long)b * V;
    const float4* votes4 = reinterpret_cast<const float4*>(votes) + bV;

    // ---- cooperative prologue: this thread owns votes va, vb (coalesced) ----
    const int va = w * 128 + lane, vb = va + 64;
    float4 v4a = votes4[va], v4b = votes4[vb];
    float sva = scales[bV + va], svb = scales[bV + vb];
    float lga = __logf(vpp[bV + va] + FEPS);
    float lgb = __logf(vpp[bV + vb] + FEPS);

    // block LSE over 513 mixing logits
    float mm = waveMaxF(fmaxf(lga, lgb));
    if (lane == 0) s_m[w] = mm;
    __syncthreads();
    float M = fmaxf(fmaxf(fmaxf(s_m[0], s_m[1]), fmaxf(s_m[2], s_m[3])), DUMMYV);
    float ss = waveSumF(__expf(lga - M) + __expf(lgb - M));
    if (lane == 0) s_s[w] = ss;
    __syncthreads();
    float S = s_s[0] + s_s[1] + s_s[2] + s_s[3] + __expf(DUMMYV - M);
    float lse = M + __logf(S);
    float dummy_post = DUMMYV + (DUMMYV - lse);

    // coefficients -> LDS (2 votes per thread, linear layout at [v+1])
    {
        float4 vv = v4a;
        float inv = frcp(sva);
        float hh = 0.5f * inv * inv;
        float c = lga - 4.0f * __logf(sva) - 2.0f * LOG_2PI - lse;
        float v2 = vv.x * vv.x + vv.y * vv.y + vv.z * vv.z + vv.w * vv.w;
        float g = 2.0f * hh * LOG2E;
        s_c2[va + 1] = (c - hh * v2 - dummy_post) * LOG2E;
        s_hk[va + 1] = -hh * LOG2E;
        s_ax[va + 1] = g * vv.x; s_ay[va + 1] = g * vv.y;
        s_az[va + 1] = g * vv.z; s_aw[va + 1] = g * vv.w;
    }
    {
        float4 vv = v4b;
        float inv = frcp(svb);
        float hh = 0.5f * inv * inv;
        float c = lgb - 4.0f * __logf(svb) - 2.0f * LOG_2PI - lse;
        float v2 = vv.x * vv.x + vv.y * vv.y + vv.z * vv.z + vv.w * vv.w;
        float g = 2.0f * hh * LOG2E;
        s_c2[vb + 1] = (c - hh * v2 - dummy_post) * LOG2E;
        s_hk[vb + 1] = -hh * LOG2E;
        s_ax[vb + 1] = g * vv.x; s_ay[vb + 1] = g * vv.y;
        s_az[vb + 1] = g * vv.z; s_aw[vb + 1] = g * vv.w;
    }

    // mixing outputs (block column 0 only; each thread its 2 votes)
    if (blockIdx.x == 0) {
        long long mb = (long long)b * (V + 1);
        out[OFF_MLOGITS  + mb + va] = lga;
        out[OFF_MLOGITS  + mb + vb] = lgb;
        out[OFF_MLOGPROB + mb + va] = lga - lse;
        out[OFF_MLOGPROB + mb + vb] = lgb - lse;
        out[OFF_VOTEPRES + bV + va] = (lga > DUMMYV) ? 1.0f : 0.0f;
        out[OFF_VOTEPRES + bV + vb] = (lgb > DUMMYV) ? 1.0f : 0.0f;
        if (t == 0) {
            out[OFF_MLOGITS  + mb + V] = DUMMYV;
            out[OFF_MLOGPROB + mb + V] = DUMMYV - lse;
        }
    }
    __syncthreads();

    // ---- per-lane coefficients from LDS, shift-3 ownership ----
    // group A: votes 3+4l..6+4l; group B: 259+4l..262+4l (lane63: 511,0,1,2)
    v4f cA, kA, xA, yA, zA, wA, cB, kB, xB, yB, zB, wB;
    {
        int oA = 4 + 4 * lane;
        cA = *reinterpret_cast<const v4f*>(&s_c2[oA]);
        kA = *reinterpret_cast<const v4f*>(&s_hk[oA]);
        xA = *reinterpret_cast<const v4f*>(&s_ax[oA]);
        yA = *reinterpret_cast<const v4f*>(&s_ay[oA]);
        zA = *reinterpret_cast<const v4f*>(&s_az[oA]);
        wA = *reinterpret_cast<const v4f*>(&s_aw[oA]);
        if (lane < 63) {
            int oB = 260 + 4 * lane;
            cB = *reinterpret_cast<const v4f*>(&s_c2[oB]);
            kB = *reinterpret_cast<const v4f*>(&s_hk[oB]);
            xB = *reinterpret_cast<const v4f*>(&s_ax[oB]);
            yB = *reinterpret_cast<const v4f*>(&s_ay[oB]);
            zB = *reinterpret_cast<const v4f*>(&s_az[oB]);
            wB = *reinterpret_cast<const v4f*>(&s_aw[oB]);
        } else {
            cB.x = s_c2[512]; cB.y = s_c2[1]; cB.z = s_c2[2]; cB.w = s_c2[3];
            kB.x = s_hk[512]; kB.y = s_hk[1]; kB.z = s_hk[2]; kB.w = s_hk[3];
            xB.x = s_ax[512]; xB.y = s_ax[1]; xB.z = s_ax[2]; xB.w = s_ax[3];
            yB.x = s_ay[512]; yB.y = s_ay[1]; yB.z = s_ay[2]; yB.w = s_ay[3];
            zB.x = s_az[512]; zB.y = s_az[1]; zB.z = s_az[2]; zB.w = s_az[3];
            wB.x = s_aw[512]; wB.y = s_aw[1]; wB.z = s_aw[2]; wB.w = s_aw[3];
        }
    }
    // flat vote indices for argmax tie-break
    int vidx[8];
    #pragma unroll
    for (int j = 0; j < 4; ++j) vidx[j] = 3 + 4 * lane + j;
    if (lane < 63) {
        #pragma unroll
        for (int j = 0; j < 4; ++j) vidx[4 + j] = 259 + 4 * lane + j;
    } else {
        vidx[4] = 511; vidx[5] = 0; vidx[6] = 1; vidx[7] = 2;
    }

    const float4* x4 = reinterpret_cast<const float4*>(x) + (long long)b * N;
    int nv = nvp[0];
    float acc = 0.f;   // lane 0 only

    #pragma unroll 2
    for (int iter = 0; iter < ROWS_PER_BLOCK / 4; ++iter) {
        int n = blockIdx.x * ROWS_PER_BLOCK + iter * 4 + w;
        long long bn = (long long)b * N + n;
        float4 xv = x4[n];
        float px2 = xv.x * xv.x + xv.y * xv.y + xv.z * xv.z + xv.w * xv.w;
        v4f P2 = {px2, px2, px2, px2};
        v4f Xx = {xv.x, xv.x, xv.x, xv.x};
        v4f Xy = {xv.y, xv.y, xv.y, xv.y};
        v4f Xz = {xv.z, xv.z, xv.z, xv.z};
        v4f Xw = {xv.w, xv.w, xv.w, xv.w};

        v4f pA = cA + kA * P2 + xA * Xx + yA * Xy + zA * Xz + wA * Xw;
        v4f pB = cB + kB * P2 + xB * Xx + yB * Xy + zB * Xz + wB * Xw;

        // row max
        v4f m4 = __builtin_elementwise_max(pA, pB);
        float m_in = fmaxf(fmaxf(m4.x, m4.y), fmaxf(m4.z, m4.w));
        float Mrow = waveMaxF(m_in);

        // exact first-occurrence argmax: min flat-vote-index among maxima
        int cand = 0x7fffffff;
        if (pA.x == Mrow) cand = min(cand, vidx[0]);
        if (pA.y == Mrow) cand = min(cand, vidx[1]);
        if (pA.z == Mrow) cand = min(cand, vidx[2]);
        if (pA.w == Mrow) cand = min(cand, vidx[3]);
        if (pB.x == Mrow) cand = min(cand, vidx[4]);
        if (pB.y == Mrow) cand = min(cand, vidx[5]);
        if (pB.z == Mrow) cand = min(cand, vidx[6]);
        if (pB.w == Mrow) cand = min(cand, vidx[7]);
        int bi = waveMinI(cand);

        // fixed-shift softmax (dummy term = exp2(0) = 1)
        v4f eA, eB;
        eA.x = fexp2(pA.x); eA.y = fexp2(pA.y); eA.z = fexp2(pA.z); eA.w = fexp2(pA.w);
        eB.x = fexp2(pB.x); eB.y = fexp2(pB.y); eB.z = fexp2(pB.z); eB.w = fexp2(pB.w);
        v4f e8 = eA + eB;
        float se = waveSumF((e8.x + e8.y) + (e8.z + e8.w));
        float total = se + 1.0f;
        float rt = frcp(total);
        v4f rtv = {rt, rt, rt, rt};

        float* rp = out + OFF_PMP + bn * (long long)V;
        v4f qa = eA * rtv, qb = eB * rtv;
        *reinterpret_cast<v4f*>(rp + 3 + 4 * lane) = qa;          // 16B-aligned
        if (lane < 63) {
            *reinterpret_cast<v4f*>(rp + 259 + 4 * lane) = qb;    // 16B-aligned
        } else {
            rp[511] = qb.x;                        // vote 511
            rp[0]   = qb.y;                        // vote 0
            v2f ez = {qb.z, qb.w};                 // votes 1,2 (8B-aligned)
            *reinterpret_cast<v2f*>(rp + 1) = ez;
        }

        if (lane == 0) {
            acc += (dummy_post + LN2 * __log2f(total)) * presence[bn];
            float4 wv = votes4[bi];
            out[OFF_WINNER + bn * 4 + 0] = wv.x;
            out[OFF_WINNER + bn * 4 + 1] = wv.y;
            out[OFF_WINNER + bn * 4 + 2] = wv.z;
            out[OFF_WINNER + bn * 4 + 3] = wv.w;
            out[OFF_WINNERPRES + bn]     = vpp[bV + bi];
            out[OFF_ISFROM + bn]         = (float)((nv == 16) ? (bi >> 4) : (bi / nv));
        }
        if (lane == 1) {
            out[OFF_ZW + bn * 4 + 0] = 0.f;
            out[OFF_ZW + bn * 4 + 1] = 0.f;
            out[OFF_ZW + bn * 4 + 2] = 0.f;
            out[OFF_ZW + bn * 4 + 3] = 0.f;
            out[OFF_ZWP + bn]        = 0.f;
        }
    }

    // ---- per-block partial -> one plain device atomicAdd (no fence!) ----
    if (lane == 0) s_part[w] = acc;
    __syncthreads();
    if (t == 0)
        atomicAdd(out + OFF_LOGPROB,
                  s_part[0] + s_part[1] + s_part[2] + s_part[3]);
}

extern "C" void kernel_launch(void* const* d_in, const int* in_sizes, int n_in,
                              void* d_out, int out_size, void* d_ws, size_t ws_size,
                              hipStream_t stream) {
    const float* x        = (const float*)d_in[0];
    const float* votes    = (const float*)d_in[1];
    const float* scales   = (const float*)d_in[2];
    const float* vpp      = (const float*)d_in[3];
    const float* presence = (const float*)d_in[4];
    const int*   nv       = (const int*)d_in[5];
    float* out = (float*)d_out;
    float* ws  = (float*)d_ws;
    (void)ws;

    // zero the log_prob accumulator (atomicAdd target) each launch
    hipMemsetAsync((void*)(out + OFF_LOGPROB), 0, sizeof(float), stream);

    dim3 g(GRID_X, B);
    k_fused<<<g, 256, 0, stream>>>(x, votes, scales, vpp, presence, nv, out, ws);
}

// Round 14
// 25.666 us; speedup vs baseline: 1.3649x; 1.3649x over previous
//
#include <hip/hip_runtime.h>

typedef float v2f __attribute__((ext_vector_type(2)));

#define FEPS 1e-16f
#define LOG_2PI 1.8378770664093453f
#define DUMMYV -4.605170185988091f   /* -2*log(10) */
#define LOG2E 1.4426950408889634f
#define LN2 0.6931471805599453f

constexpr int B = 32, N = 1024, V = 512;
constexpr int ROWS_PER_BLOCK = 32;
constexpr int GRID_X = N / ROWS_PER_BLOCK;   // 32 -> 1024 blocks (proven best)

constexpr long long OFF_LOGPROB    = 0;
constexpr long long OFF_VOTEPRES   = 1;
constexpr long long OFF_WINNER     = OFF_VOTEPRES + (long long)B * V;
constexpr long long OFF_WINNERPRES = OFF_WINNER + (long long)B * N * 4;
constexpr long long OFF_ISFROM     = OFF_WINNERPRES + (long long)B * N;
constexpr long long OFF_MLOGITS    = OFF_ISFROM + (long long)B * N;
constexpr long long OFF_MLOGPROB   = OFF_MLOGITS + (long long)B * (V + 1);
constexpr long long OFF_ZW         = OFF_MLOGPROB + (long long)B * (V + 1);
constexpr long long OFF_ZWP        = OFF_ZW + (long long)B * N * 4;
constexpr long long OFF_PMP        = OFF_ZWP + (long long)B * N;

__device__ __forceinline__ float fexp2(float x) {
#if __has_builtin(__builtin_amdgcn_exp2f)
    return __builtin_amdgcn_exp2f(x);
#else
    return __expf(x * LN2);
#endif
}
__device__ __forceinline__ float frcp(float x) {
#if __has_builtin(__builtin_amdgcn_rcpf)
    return __builtin_amdgcn_rcpf(x);
#else
    return 1.0f / x;
#endif
}

template<int RN> __device__ __forceinline__ float dppRorF(float x) {
    return __int_as_float(__builtin_amdgcn_update_dpp(
        0, __float_as_int(x), 0x120 | RN, 0xF, 0xF, false));
}
template<int RN> __device__ __forceinline__ int dppRorI(int x) {
    return __builtin_amdgcn_update_dpp(0, x, 0x120 | RN, 0xF, 0xF, false);
}
// xor-16 butterfly step via ds_swizzle bitmode: offset = (16<<10)|0x1F
__device__ __forceinline__ float swz16F(float x) {
    return __int_as_float(__builtin_amdgcn_ds_swizzle(__float_as_int(x), 0x401F));
}
__device__ __forceinline__ int swz16I(int x) {
    return __builtin_amdgcn_ds_swizzle(x, 0x401F);
}

// xor-32 step: permlane32_swap (VALU pipe) if available, else shfl (LDS pipe)
#if __has_builtin(__builtin_amdgcn_permlane32_swap)
__device__ __forceinline__ float maxSwap32(float x) {
    auto r = __builtin_amdgcn_permlane32_swap(__float_as_uint(x), __float_as_uint(x), false, false);
    return fmaxf(__uint_as_float(r[0]), __uint_as_float(r[1]));
}
__device__ __forceinline__ float sumSwap32(float x) {
    auto r = __builtin_amdgcn_permlane32_swap(__float_as_uint(x), __float_as_uint(x), false, false);
    return __uint_as_float(r[0]) + __uint_as_float(r[1]);
}
__device__ __forceinline__ int minSwap32(int x) {
    auto r = __builtin_amdgcn_permlane32_swap((unsigned)x, (unsigned)x, false, false);
    int a = (int)r[0], b = (int)r[1];
    return a < b ? a : b;
}
#else
__device__ __forceinline__ float maxSwap32(float x) { return fmaxf(x, __shfl_xor(x, 32)); }
__device__ __forceinline__ float sumSwap32(float x) { return x + __shfl_xor(x, 32); }
__device__ __forceinline__ int   minSwap32(int x)   { int o = __shfl_xor(x, 32); return o < x ? o : x; }
#endif

// paired reduces: two independent chains interleaved (halves exposed latency)
__device__ __forceinline__ void waveMaxF2(float& a, float& b) {
    a = fmaxf(a, dppRorF<1>(a)); b = fmaxf(b, dppRorF<1>(b));
    a = fmaxf(a, dppRorF<2>(a)); b = fmaxf(b, dppRorF<2>(b));
    a = fmaxf(a, dppRorF<4>(a)); b = fmaxf(b, dppRorF<4>(b));
    a = fmaxf(a, dppRorF<8>(a)); b = fmaxf(b, dppRorF<8>(b));
    a = fmaxf(a, swz16F(a));     b = fmaxf(b, swz16F(b));
    a = maxSwap32(a);            b = maxSwap32(b);
}
__device__ __forceinline__ void waveSumF2(float& a, float& b) {
    a += dppRorF<1>(a); b += dppRorF<1>(b);
    a += dppRorF<2>(a); b += dppRorF<2>(b);
    a += dppRorF<4>(a); b += dppRorF<4>(b);
    a += dppRorF<8>(a); b += dppRorF<8>(b);
    a += swz16F(a);     b += swz16F(b);
    a = sumSwap32(a);   b = sumSwap32(b);
}
__device__ __forceinline__ void waveMinI2(int& a, int& b) {
    int oa, ob;
    oa = dppRorI<1>(a); ob = dppRorI<1>(b); a = oa < a ? oa : a; b = ob < b ? ob : b;
    oa = dppRorI<2>(a); ob = dppRorI<2>(b); a = oa < a ? oa : a; b = ob < b ? ob : b;
    oa = dppRorI<4>(a); ob = dppRorI<4>(b); a = oa < a ? oa : a; b = ob < b ? ob : b;
    oa = dppRorI<8>(a); ob = dppRorI<8>(b); a = oa < a ? oa : a; b = ob < b ? ob : b;
    oa = swz16I(a);     ob = swz16I(b);     a = oa < a ? oa : a; b = ob < b ? ob : b;
    a = minSwap32(a);   b = minSwap32(b);
}

__device__ __forceinline__ float waveMaxF(float m) {
    m = fmaxf(m, dppRorF<1>(m));
    m = fmaxf(m, dppRorF<2>(m));
    m = fmaxf(m, dppRorF<4>(m));
    m = fmaxf(m, dppRorF<8>(m));
    m = fmaxf(m, swz16F(m));
    return maxSwap32(m);
}
__device__ __forceinline__ float waveSumF(float s) {
    s += dppRorF<1>(s);
    s += dppRorF<2>(s);
    s += dppRorF<4>(s);
    s += dppRorF<8>(s);
    s += swz16F(s);
    return sumSwap32(s);
}

__global__ __launch_bounds__(256) void k_fused(const float* __restrict__ x,
                                               const float* __restrict__ votes,
                                               const float* __restrict__ scales,
                                               const float* __restrict__ vpp,
                                               const float* __restrict__ presence,
                                               const int* __restrict__ nvp,
                                               float* __restrict__ out,
                                               float* __restrict__ ws) {
    // 6 coeff arrays, layout [i=k>>1][lane][h=k&1] so each lane's pair
    // (k=2i,k=2i+1) is one 2-way-aliased (free) ds_read_b64.
    __shared__ float s_c2[512], s_hk[512], s_ax[512], s_ay[512], s_az[512], s_aw[512];
    __shared__ float s_m[4], s_s[4], s_part[4];

    const int b = blockIdx.y, t = threadIdx.x, w = t >> 6, lane = t & 63;
    const long long bV = (long long)b * V;
    const float4* votes4 = reinterpret_cast<const float4*>(votes) + bV;

    // ---- cooperative prologue: this thread owns votes va, vb (coalesced) ----
    const int va = w * 128 + lane, vb = va + 64;
    float4 v4a = votes4[va], v4b = votes4[vb];
    float sva = scales[bV + va], svb = scales[bV + vb];
    float lga = __logf(vpp[bV + va] + FEPS);
    float lgb = __logf(vpp[bV + vb] + FEPS);

    // block LSE over 513 mixing logits
    float mm = waveMaxF(fmaxf(lga, lgb));
    if (lane == 0) s_m[w] = mm;
    __syncthreads();
    float M = fmaxf(fmaxf(fmaxf(s_m[0], s_m[1]), fmaxf(s_m[2], s_m[3])), DUMMYV);
    float ss = waveSumF(__expf(lga - M) + __expf(lgb - M));
    if (lane == 0) s_s[w] = ss;
    __syncthreads();
    float S = s_s[0] + s_s[1] + s_s[2] + s_s[3] + __expf(DUMMYV - M);
    float lse = M + __logf(S);
    float dummy_post = DUMMYV + (DUMMYV - lse);

    // coefficients -> LDS (2 votes per thread)
    {
        float4 vv = v4a;
        float inv = frcp(sva);
        float hh = 0.5f * inv * inv;
        float c = lga - 4.0f * __logf(sva) - 2.0f * LOG_2PI - lse;
        float v2 = vv.x * vv.x + vv.y * vv.y + vv.z * vv.z + vv.w * vv.w;
        int idx = ((va >> 7) << 7) + ((va & 63) << 1) + ((va >> 6) & 1);
        float g = 2.0f * hh * LOG2E;
        s_c2[idx] = (c - hh * v2 - dummy_post) * LOG2E;
        s_hk[idx] = -hh * LOG2E;
        s_ax[idx] = g * vv.x; s_ay[idx] = g * vv.y;
        s_az[idx] = g * vv.z; s_aw[idx] = g * vv.w;
    }
    {
        float4 vv = v4b;
        float inv = frcp(svb);
        float hh = 0.5f * inv * inv;
        float c = lgb - 4.0f * __logf(svb) - 2.0f * LOG_2PI - lse;
        float v2 = vv.x * vv.x + vv.y * vv.y + vv.z * vv.z + vv.w * vv.w;
        int idx = ((vb >> 7) << 7) + ((vb & 63) << 1) + ((vb >> 6) & 1);
        float g = 2.0f * hh * LOG2E;
        s_c2[idx] = (c - hh * v2 - dummy_post) * LOG2E;
        s_hk[idx] = -hh * LOG2E;
        s_ax[idx] = g * vv.x; s_ay[idx] = g * vv.y;
        s_az[idx] = g * vv.z; s_aw[idx] = g * vv.w;
    }

    // mixing outputs (block column 0 only; each thread its 2 votes)
    if (blockIdx.x == 0) {
        long long mb = (long long)b * (V + 1);
        out[OFF_MLOGITS  + mb + va] = lga;
        out[OFF_MLOGITS  + mb + vb] = lgb;
        out[OFF_MLOGPROB + mb + va] = lga - lse;
        out[OFF_MLOGPROB + mb + vb] = lgb - lse;
        out[OFF_VOTEPRES + bV + va] = (lga > DUMMYV) ? 1.0f : 0.0f;
        out[OFF_VOTEPRES + bV + vb] = (lgb > DUMMYV) ? 1.0f : 0.0f;
        if (t == 0) {
            out[OFF_MLOGITS  + mb + V] = DUMMYV;
            out[OFF_MLOGPROB + mb + V] = DUMMYV - lse;
        }
    }
    __syncthreads();

    // ---- per-lane packed constants from LDS (ownership v = k*64 + lane) ----
    v2f c2[4], hk[4], hvx[4], hvy[4], hvz[4], hvw[4];
    #pragma unroll
    for (int i = 0; i < 4; ++i) {
        int o = i * 128 + lane * 2;
        c2[i]  = *reinterpret_cast<const v2f*>(&s_c2[o]);
        hk[i]  = *reinterpret_cast<const v2f*>(&s_hk[o]);
        hvx[i] = *reinterpret_cast<const v2f*>(&s_ax[o]);
        hvy[i] = *reinterpret_cast<const v2f*>(&s_ay[o]);
        hvz[i] = *reinterpret_cast<const v2f*>(&s_az[o]);
        hvw[i] = *reinterpret_cast<const v2f*>(&s_aw[o]);
    }

    const float4* x4 = reinterpret_cast<const float4*>(x) + (long long)b * N;
    int nv = nvp[0];
    float acc = 0.f;   // lane 0 only

    // 4 iterations x 2 rows in lock-step: the two rows' reduce trees are
    // independent chains, explicitly interleaved to halve exposed latency.
    for (int iter = 0; iter < ROWS_PER_BLOCK / 8; ++iter) {
        int n0 = blockIdx.x * ROWS_PER_BLOCK + iter * 8 + w;
        int n1 = n0 + 4;
        long long bn0 = (long long)b * N + n0;
        long long bn1 = (long long)b * N + n1;
        float4 xv0 = x4[n0];
        float4 xv1 = x4[n1];

        float p0[8], p1[8];
        {
            float px0 = xv0.x * xv0.x + xv0.y * xv0.y + xv0.z * xv0.z + xv0.w * xv0.w;
            float px1 = xv1.x * xv1.x + xv1.y * xv1.y + xv1.z * xv1.z + xv1.w * xv1.w;
            #pragma unroll
            for (int i = 0; i < 4; ++i) {
                v2f t0 = c2[i], t1 = c2[i];
                v2f K = hk[i], X = hvx[i], Y = hvy[i], Z = hvz[i], W = hvw[i];
                t0 += K * (v2f){px0, px0};   t1 += K * (v2f){px1, px1};
                t0 += X * (v2f){xv0.x, xv0.x}; t1 += X * (v2f){xv1.x, xv1.x};
                t0 += Y * (v2f){xv0.y, xv0.y}; t1 += Y * (v2f){xv1.y, xv1.y};
                t0 += Z * (v2f){xv0.z, xv0.z}; t1 += Z * (v2f){xv1.z, xv1.z};
                t0 += W * (v2f){xv0.w, xv0.w}; t1 += W * (v2f){xv1.w, xv1.w};
                p0[2 * i] = t0.x; p0[2 * i + 1] = t0.y;
                p1[2 * i] = t1.x; p1[2 * i + 1] = t1.y;
            }
        }

        // in-lane max trees (independent), then paired wave max
        float a1 = fmaxf(fmaxf(p0[0], p0[1]), p0[2]);
        float a2 = fmaxf(fmaxf(p0[3], p0[4]), p0[5]);
        float a3 = fmaxf(fmaxf(p0[6], p0[7]), a1);
        float m0 = fmaxf(a2, a3);
        float b1 = fmaxf(fmaxf(p1[0], p1[1]), p1[2]);
        float b2 = fmaxf(fmaxf(p1[3], p1[4]), p1[5]);
        float b3 = fmaxf(fmaxf(p1[6], p1[7]), b1);
        float m1 = fmaxf(b2, b3);
        waveMaxF2(m0, m1);

        // exact first-occurrence argmax for both rows
        int c0 = 0x7fffffff, c1 = 0x7fffffff;
        #pragma unroll
        for (int k = 0; k < 8; ++k) {
            int fi = k * 64 + lane;
            if (p0[k] == m0 && fi < c0) c0 = fi;
            if (p1[k] == m1 && fi < c1) c1 = fi;
        }
        waveMinI2(c0, c1);

        // fixed-shift softmax for both rows
        float e0[8], e1[8];
        float s0 = 0.f, s1 = 0.f;
        #pragma unroll
        for (int k = 0; k < 8; ++k) {
            e0[k] = fexp2(p0[k]); s0 += e0[k];
            e1[k] = fexp2(p1[k]); s1 += e1[k];
        }
        waveSumF2(s0, s1);
        float tot0 = s0 + 1.0f, tot1 = s1 + 1.0f;
        float rt0 = frcp(tot0), rt1 = frcp(tot1);

        long long pb0 = OFF_PMP + bn0 * (long long)V;
        long long pb1 = OFF_PMP + bn1 * (long long)V;
        #pragma unroll
        for (int k = 0; k < 8; ++k) {
            out[pb0 + k * 64 + lane] = e0[k] * rt0;   // 256B contiguous/instr
            out[pb1 + k * 64 + lane] = e1[k] * rt1;
        }

        if (lane == 0) {
            acc += (dummy_post + LN2 * __log2f(tot0)) * presence[bn0];
            acc += (dummy_post + LN2 * __log2f(tot1)) * presence[bn1];
            float4 wv0 = votes4[c0];
            out[OFF_WINNER + bn0 * 4 + 0] = wv0.x;
            out[OFF_WINNER + bn0 * 4 + 1] = wv0.y;
            out[OFF_WINNER + bn0 * 4 + 2] = wv0.z;
            out[OFF_WINNER + bn0 * 4 + 3] = wv0.w;
            out[OFF_WINNERPRES + bn0]     = vpp[bV + c0];
            out[OFF_ISFROM + bn0]         = (float)((nv == 16) ? (c0 >> 4) : (c0 / nv));
            float4 wv1 = votes4[c1];
            out[OFF_WINNER + bn1 * 4 + 0] = wv1.x;
            out[OFF_WINNER + bn1 * 4 + 1] = wv1.y;
            out[OFF_WINNER + bn1 * 4 + 2] = wv1.z;
            out[OFF_WINNER + bn1 * 4 + 3] = wv1.w;
            out[OFF_WINNERPRES + bn1]     = vpp[bV + c1];
            out[OFF_ISFROM + bn1]         = (float)((nv == 16) ? (c1 >> 4) : (c1 / nv));
        }
        if (lane == 1) {
            out[OFF_ZW + bn0 * 4 + 0] = 0.f;
            out[OFF_ZW + bn0 * 4 + 1] = 0.f;
            out[OFF_ZW + bn0 * 4 + 2] = 0.f;
            out[OFF_ZW + bn0 * 4 + 3] = 0.f;
            out[OFF_ZWP + bn0]        = 0.f;
            out[OFF_ZW + bn1 * 4 + 0] = 0.f;
            out[OFF_ZW + bn1 * 4 + 1] = 0.f;
            out[OFF_ZW + bn1 * 4 + 2] = 0.f;
            out[OFF_ZW + bn1 * 4 + 3] = 0.f;
            out[OFF_ZWP + bn1]        = 0.f;
        }
    }

    if (lane == 0) s_part[w] = acc;
    __syncthreads();
    if (t == 0)
        ws[(long long)b * gridDim.x + blockIdx.x] =
            s_part[0] + s_part[1] + s_part[2] + s_part[3];
}

__global__ __launch_bounds__(256) void k_reduce(const float* __restrict__ ws,
                                                float* __restrict__ out, int count) {
    __shared__ float sred[256];
    int t = threadIdx.x;
    float s = 0.f;
    for (int i = t; i < count; i += 256) s += ws[i];
    sred[t] = s;
    __syncthreads();
    for (int o = 128; o > 0; o >>= 1) {
        if (t < o) sred[t] += sred[t + o];
        __syncthreads();
    }
    if (t == 0) out[OFF_LOGPROB] = sred[0];
}

extern "C" void kernel_launch(void* const* d_in, const int* in_sizes, int n_in,
                              void* d_out, int out_size, void* d_ws, size_t ws_size,
                              hipStream_t stream) {
    const float* x        = (const float*)d_in[0];
    const float* votes    = (const float*)d_in[1];
    const float* scales   = (const float*)d_in[2];
    const float* vpp      = (const float*)d_in[3];
    const float* presence = (const float*)d_in[4];
    const int*   nv       = (const int*)d_in[5];
    float* out = (float*)d_out;
    float* ws  = (float*)d_ws;

    dim3 g(GRID_X, B);
    k_fused<<<g, 256, 0, stream>>>(x, votes, scales, vpp, presence, nv, out, ws);
    k_reduce<<<1, 256, 0, stream>>>(ws, out, GRID_X * B);
}

// Round 15
// 25.296 us; speedup vs baseline: 1.3848x; 1.0146x over previous
//
#include <hip/hip_runtime.h>

typedef float v2f __attribute__((ext_vector_type(2)));

#define FEPS 1e-16f
#define LOG_2PI 1.8378770664093453f
#define DUMMYV -4.605170185988091f   /* -2*log(10) */
#define LOG2E 1.4426950408889634f
#define LN2 0.6931471805599453f

constexpr int B = 32, N = 1024, V = 512;
constexpr int ROWS_PER_BLOCK = 32;
constexpr int GRID_X = N / ROWS_PER_BLOCK;   // 32 -> 1024 blocks (proven best)

constexpr long long OFF_LOGPROB    = 0;
constexpr long long OFF_VOTEPRES   = 1;
constexpr long long OFF_WINNER     = OFF_VOTEPRES + (long long)B * V;
constexpr long long OFF_WINNERPRES = OFF_WINNER + (long long)B * N * 4;
constexpr long long OFF_ISFROM     = OFF_WINNERPRES + (long long)B * N;
constexpr long long OFF_MLOGITS    = OFF_ISFROM + (long long)B * N;
constexpr long long OFF_MLOGPROB   = OFF_MLOGITS + (long long)B * (V + 1);
constexpr long long OFF_ZW         = OFF_MLOGPROB + (long long)B * (V + 1);
constexpr long long OFF_ZWP        = OFF_ZW + (long long)B * N * 4;
constexpr long long OFF_PMP        = OFF_ZWP + (long long)B * N;

__device__ __forceinline__ float fexp2(float x) {
#if __has_builtin(__builtin_amdgcn_exp2f)
    return __builtin_amdgcn_exp2f(x);
#else
    return __expf(x * LN2);
#endif
}
__device__ __forceinline__ float frcp(float x) {
#if __has_builtin(__builtin_amdgcn_rcpf)
    return __builtin_amdgcn_rcpf(x);
#else
    return 1.0f / x;
#endif
}

template<int RN> __device__ __forceinline__ float dppRorF(float x) {
    return __int_as_float(__builtin_amdgcn_update_dpp(
        0, __float_as_int(x), 0x120 | RN, 0xF, 0xF, false));
}
template<int RN> __device__ __forceinline__ int dppRorI(int x) {
    return __builtin_amdgcn_update_dpp(0, x, 0x120 | RN, 0xF, 0xF, false);
}
// xor-16 butterfly step via ds_swizzle bitmode: offset = (16<<10)|0x1F
__device__ __forceinline__ float swz16F(float x) {
    return __int_as_float(__builtin_amdgcn_ds_swizzle(__float_as_int(x), 0x401F));
}
__device__ __forceinline__ int swz16I(int x) {
    return __builtin_amdgcn_ds_swizzle(x, 0x401F);
}

// xor-32 step: permlane32_swap (VALU pipe) if available, else shfl (LDS pipe)
#if __has_builtin(__builtin_amdgcn_permlane32_swap)
__device__ __forceinline__ float maxSwap32(float x) {
    auto r = __builtin_amdgcn_permlane32_swap(__float_as_uint(x), __float_as_uint(x), false, false);
    return fmaxf(__uint_as_float(r[0]), __uint_as_float(r[1]));
}
__device__ __forceinline__ float sumSwap32(float x) {
    auto r = __builtin_amdgcn_permlane32_swap(__float_as_uint(x), __float_as_uint(x), false, false);
    return __uint_as_float(r[0]) + __uint_as_float(r[1]);
}
__device__ __forceinline__ int minSwap32(int x) {
    auto r = __builtin_amdgcn_permlane32_swap((unsigned)x, (unsigned)x, false, false);
    int a = (int)r[0], b = (int)r[1];
    return a < b ? a : b;
}
#else
__device__ __forceinline__ float maxSwap32(float x) { return fmaxf(x, __shfl_xor(x, 32)); }
__device__ __forceinline__ float sumSwap32(float x) { return x + __shfl_xor(x, 32); }
__device__ __forceinline__ int   minSwap32(int x)   { int o = __shfl_xor(x, 32); return o < x ? o : x; }
#endif

// paired reduces: two independent chains interleaved (halves exposed latency)
__device__ __forceinline__ void waveMaxF2(float& a, float& b) {
    a = fmaxf(a, dppRorF<1>(a)); b = fmaxf(b, dppRorF<1>(b));
    a = fmaxf(a, dppRorF<2>(a)); b = fmaxf(b, dppRorF<2>(b));
    a = fmaxf(a, dppRorF<4>(a)); b = fmaxf(b, dppRorF<4>(b));
    a = fmaxf(a, dppRorF<8>(a)); b = fmaxf(b, dppRorF<8>(b));
    a = fmaxf(a, swz16F(a));     b = fmaxf(b, swz16F(b));
    a = maxSwap32(a);            b = maxSwap32(b);
}
__device__ __forceinline__ void waveSumF2(float& a, float& b) {
    a += dppRorF<1>(a); b += dppRorF<1>(b);
    a += dppRorF<2>(a); b += dppRorF<2>(b);
    a += dppRorF<4>(a); b += dppRorF<4>(b);
    a += dppRorF<8>(a); b += dppRorF<8>(b);
    a += swz16F(a);     b += swz16F(b);
    a = sumSwap32(a);   b = sumSwap32(b);
}
__device__ __forceinline__ void waveMinI2(int& a, int& b) {
    int oa, ob;
    oa = dppRorI<1>(a); ob = dppRorI<1>(b); a = oa < a ? oa : a; b = ob < b ? ob : b;
    oa = dppRorI<2>(a); ob = dppRorI<2>(b); a = oa < a ? oa : a; b = ob < b ? ob : b;
    oa = dppRorI<4>(a); ob = dppRorI<4>(b); a = oa < a ? oa : a; b = ob < b ? ob : b;
    oa = dppRorI<8>(a); ob = dppRorI<8>(b); a = oa < a ? oa : a; b = ob < b ? ob : b;
    oa = swz16I(a);     ob = swz16I(b);     a = oa < a ? oa : a; b = ob < b ? ob : b;
    a = minSwap32(a);   b = minSwap32(b);
}

__device__ __forceinline__ float waveMaxF(float m) {
    m = fmaxf(m, dppRorF<1>(m));
    m = fmaxf(m, dppRorF<2>(m));
    m = fmaxf(m, dppRorF<4>(m));
    m = fmaxf(m, dppRorF<8>(m));
    m = fmaxf(m, swz16F(m));
    return maxSwap32(m);
}
__device__ __forceinline__ float waveSumF(float s) {
    s += dppRorF<1>(s);
    s += dppRorF<2>(s);
    s += dppRorF<4>(s);
    s += dppRorF<8>(s);
    s += swz16F(s);
    return sumSwap32(s);
}

// (256,4): cap VGPR at 128 so all 4 blocks/CU are co-resident (single batch,
// full store/VALU overlap). Coop prologue keeps the live set small, so the
// cap should not force spills (unlike R10's attempt on the R4 structure).
__global__ __launch_bounds__(256, 4) void k_fused(const float* __restrict__ x,
                                               const float* __restrict__ votes,
                                               const float* __restrict__ scales,
                                               const float* __restrict__ vpp,
                                               const float* __restrict__ presence,
                                               const int* __restrict__ nvp,
                                               float* __restrict__ out,
                                               float* __restrict__ ws) {
    // 6 coeff arrays, layout [i=k>>1][lane][h=k&1] so each lane's pair
    // (k=2i,k=2i+1) is one 2-way-aliased (free) ds_read_b64.
    __shared__ float s_c2[512], s_hk[512], s_ax[512], s_ay[512], s_az[512], s_aw[512];
    __shared__ float s_m[4], s_s[4], s_part[4];

    const int b = blockIdx.y, t = threadIdx.x, w = t >> 6, lane = t & 63;
    const long long bV = (long long)b * V;
    const float4* votes4 = reinterpret_cast<const float4*>(votes) + bV;

    // ---- cooperative prologue: this thread owns votes va, vb (coalesced) ----
    const int va = w * 128 + lane, vb = va + 64;
    float4 v4a = votes4[va], v4b = votes4[vb];
    float sva = scales[bV + va], svb = scales[bV + vb];
    float lga = __logf(vpp[bV + va] + FEPS);
    float lgb = __logf(vpp[bV + vb] + FEPS);

    // block LSE over 513 mixing logits
    float mm = waveMaxF(fmaxf(lga, lgb));
    if (lane == 0) s_m[w] = mm;
    __syncthreads();
    float M = fmaxf(fmaxf(fmaxf(s_m[0], s_m[1]), fmaxf(s_m[2], s_m[3])), DUMMYV);
    float ss = waveSumF(__expf(lga - M) + __expf(lgb - M));
    if (lane == 0) s_s[w] = ss;
    __syncthreads();
    float S = s_s[0] + s_s[1] + s_s[2] + s_s[3] + __expf(DUMMYV - M);
    float lse = M + __logf(S);
    float dummy_post = DUMMYV + (DUMMYV - lse);

    // coefficients -> LDS (2 votes per thread)
    {
        float4 vv = v4a;
        float inv = frcp(sva);
        float hh = 0.5f * inv * inv;
        float c = lga - 4.0f * __logf(sva) - 2.0f * LOG_2PI - lse;
        float v2 = vv.x * vv.x + vv.y * vv.y + vv.z * vv.z + vv.w * vv.w;
        int idx = ((va >> 7) << 7) + ((va & 63) << 1) + ((va >> 6) & 1);
        float g = 2.0f * hh * LOG2E;
        s_c2[idx] = (c - hh * v2 - dummy_post) * LOG2E;
        s_hk[idx] = -hh * LOG2E;
        s_ax[idx] = g * vv.x; s_ay[idx] = g * vv.y;
        s_az[idx] = g * vv.z; s_aw[idx] = g * vv.w;
    }
    {
        float4 vv = v4b;
        float inv = frcp(svb);
        float hh = 0.5f * inv * inv;
        float c = lgb - 4.0f * __logf(svb) - 2.0f * LOG_2PI - lse;
        float v2 = vv.x * vv.x + vv.y * vv.y + vv.z * vv.z + vv.w * vv.w;
        int idx = ((vb >> 7) << 7) + ((vb & 63) << 1) + ((vb >> 6) & 1);
        float g = 2.0f * hh * LOG2E;
        s_c2[idx] = (c - hh * v2 - dummy_post) * LOG2E;
        s_hk[idx] = -hh * LOG2E;
        s_ax[idx] = g * vv.x; s_ay[idx] = g * vv.y;
        s_az[idx] = g * vv.z; s_aw[idx] = g * vv.w;
    }

    // mixing outputs (block column 0 only; each thread its 2 votes)
    if (blockIdx.x == 0) {
        long long mb = (long long)b * (V + 1);
        out[OFF_MLOGITS  + mb + va] = lga;
        out[OFF_MLOGITS  + mb + vb] = lgb;
        out[OFF_MLOGPROB + mb + va] = lga - lse;
        out[OFF_MLOGPROB + mb + vb] = lgb - lse;
        out[OFF_VOTEPRES + bV + va] = (lga > DUMMYV) ? 1.0f : 0.0f;
        out[OFF_VOTEPRES + bV + vb] = (lgb > DUMMYV) ? 1.0f : 0.0f;
        if (t == 0) {
            out[OFF_MLOGITS  + mb + V] = DUMMYV;
            out[OFF_MLOGPROB + mb + V] = DUMMYV - lse;
        }
    }
    __syncthreads();

    // ---- per-lane packed constants from LDS (ownership v = k*64 + lane) ----
    v2f c2[4], hk[4], hvx[4], hvy[4], hvz[4], hvw[4];
    #pragma unroll
    for (int i = 0; i < 4; ++i) {
        int o = i * 128 + lane * 2;
        c2[i]  = *reinterpret_cast<const v2f*>(&s_c2[o]);
        hk[i]  = *reinterpret_cast<const v2f*>(&s_hk[o]);
        hvx[i] = *reinterpret_cast<const v2f*>(&s_ax[o]);
        hvy[i] = *reinterpret_cast<const v2f*>(&s_ay[o]);
        hvz[i] = *reinterpret_cast<const v2f*>(&s_az[o]);
        hvw[i] = *reinterpret_cast<const v2f*>(&s_aw[o]);
    }

    const float4* x4 = reinterpret_cast<const float4*>(x) + (long long)b * N;
    int nv = nvp[0];
    float acc = 0.f;   // lane 0 only

    // 4 iterations x 2 rows in lock-step: the two rows' reduce trees are
    // independent chains, explicitly interleaved to halve exposed latency.
    for (int iter = 0; iter < ROWS_PER_BLOCK / 8; ++iter) {
        int n0 = blockIdx.x * ROWS_PER_BLOCK + iter * 8 + w;
        int n1 = n0 + 4;
        long long bn0 = (long long)b * N + n0;
        long long bn1 = (long long)b * N + n1;
        float4 xv0 = x4[n0];
        float4 xv1 = x4[n1];

        float p0[8], p1[8];
        {
            float px0 = xv0.x * xv0.x + xv0.y * xv0.y + xv0.z * xv0.z + xv0.w * xv0.w;
            float px1 = xv1.x * xv1.x + xv1.y * xv1.y + xv1.z * xv1.z + xv1.w * xv1.w;
            #pragma unroll
            for (int i = 0; i < 4; ++i) {
                v2f t0 = c2[i], t1 = c2[i];
                v2f K = hk[i], X = hvx[i], Y = hvy[i], Z = hvz[i], W = hvw[i];
                t0 += K * (v2f){px0, px0};   t1 += K * (v2f){px1, px1};
                t0 += X * (v2f){xv0.x, xv0.x}; t1 += X * (v2f){xv1.x, xv1.x};
                t0 += Y * (v2f){xv0.y, xv0.y}; t1 += Y * (v2f){xv1.y, xv1.y};
                t0 += Z * (v2f){xv0.z, xv0.z}; t1 += Z * (v2f){xv1.z, xv1.z};
                t0 += W * (v2f){xv0.w, xv0.w}; t1 += W * (v2f){xv1.w, xv1.w};
                p0[2 * i] = t0.x; p0[2 * i + 1] = t0.y;
                p1[2 * i] = t1.x; p1[2 * i + 1] = t1.y;
            }
        }

        // in-lane max trees (independent), then paired wave max
        float a1 = fmaxf(fmaxf(p0[0], p0[1]), p0[2]);
        float a2 = fmaxf(fmaxf(p0[3], p0[4]), p0[5]);
        float a3 = fmaxf(fmaxf(p0[6], p0[7]), a1);
        float m0 = fmaxf(a2, a3);
        float b1 = fmaxf(fmaxf(p1[0], p1[1]), p1[2]);
        float b2 = fmaxf(fmaxf(p1[3], p1[4]), p1[5]);
        float b3 = fmaxf(fmaxf(p1[6], p1[7]), b1);
        float m1 = fmaxf(b2, b3);
        waveMaxF2(m0, m1);

        // exact first-occurrence argmax for both rows
        int c0 = 0x7fffffff, c1 = 0x7fffffff;
        #pragma unroll
        for (int k = 0; k < 8; ++k) {
            int fi = k * 64 + lane;
            if (p0[k] == m0 && fi < c0) c0 = fi;
            if (p1[k] == m1 && fi < c1) c1 = fi;
        }
        waveMinI2(c0, c1);

        // fixed-shift softmax for both rows
        float e0[8], e1[8];
        float s0 = 0.f, s1 = 0.f;
        #pragma unroll
        for (int k = 0; k < 8; ++k) {
            e0[k] = fexp2(p0[k]); s0 += e0[k];
            e1[k] = fexp2(p1[k]); s1 += e1[k];
        }
        waveSumF2(s0, s1);
        float tot0 = s0 + 1.0f, tot1 = s1 + 1.0f;
        float rt0 = frcp(tot0), rt1 = frcp(tot1);

        long long pb0 = OFF_PMP + bn0 * (long long)V;
        long long pb1 = OFF_PMP + bn1 * (long long)V;
        #pragma unroll
        for (int k = 0; k < 8; ++k) {
            out[pb0 + k * 64 + lane] = e0[k] * rt0;   // 256B contiguous/instr
            out[pb1 + k * 64 + lane] = e1[k] * rt1;
        }

        if (lane == 0) {
            acc += (dummy_post + LN2 * __log2f(tot0)) * presence[bn0];
            acc += (dummy_post + LN2 * __log2f(tot1)) * presence[bn1];
            float4 wv0 = votes4[c0];
            out[OFF_WINNER + bn0 * 4 + 0] = wv0.x;
            out[OFF_WINNER + bn0 * 4 + 1] = wv0.y;
            out[OFF_WINNER + bn0 * 4 + 2] = wv0.z;
            out[OFF_WINNER + bn0 * 4 + 3] = wv0.w;
            out[OFF_WINNERPRES + bn0]     = vpp[bV + c0];
            out[OFF_ISFROM + bn0]         = (float)((nv == 16) ? (c0 >> 4) : (c0 / nv));
            float4 wv1 = votes4[c1];
            out[OFF_WINNER + bn1 * 4 + 0] = wv1.x;
            out[OFF_WINNER + bn1 * 4 + 1] = wv1.y;
            out[OFF_WINNER + bn1 * 4 + 2] = wv1.z;
            out[OFF_WINNER + bn1 * 4 + 3] = wv1.w;
            out[OFF_WINNERPRES + bn1]     = vpp[bV + c1];
            out[OFF_ISFROM + bn1]         = (float)((nv == 16) ? (c1 >> 4) : (c1 / nv));
        }
        if (lane == 1) {
            out[OFF_ZW + bn0 * 4 + 0] = 0.f;
            out[OFF_ZW + bn0 * 4 + 1] = 0.f;
            out[OFF_ZW + bn0 * 4 + 2] = 0.f;
            out[OFF_ZW + bn0 * 4 + 3] = 0.f;
            out[OFF_ZWP + bn0]        = 0.f;
            out[OFF_ZW + bn1 * 4 + 0] = 0.f;
            out[OFF_ZW + bn1 * 4 + 1] = 0.f;
            out[OFF_ZW + bn1 * 4 + 2] = 0.f;
            out[OFF_ZW + bn1 * 4 + 3] = 0.f;
            out[OFF_ZWP + bn1]        = 0.f;
        }
    }

    if (lane == 0) s_part[w] = acc;
    __syncthreads();
    if (t == 0)
        ws[(long long)b * gridDim.x + blockIdx.x] =
            s_part[0] + s_part[1] + s_part[2] + s_part[3];
}

__global__ __launch_bounds__(256) void k_reduce(const float* __restrict__ ws,
                                                float* __restrict__ out, int count) {
    __shared__ float sred[256];
    int t = threadIdx.x;
    float s = 0.f;
    for (int i = t; i < count; i += 256) s += ws[i];
    sred[t] = s;
    __syncthreads();
    for (int o = 128; o > 0; o >>= 1) {
        if (t < o) sred[t] += sred[t + o];
        __syncthreads();
    }
    if (t == 0) out[OFF_LOGPROB] = sred[0];
}

extern "C" void kernel_launch(void* const* d_in, const int* in_sizes, int n_in,
                              void* d_out, int out_size, void* d_ws, size_t ws_size,
                              hipStream_t stream) {
    const float* x        = (const float*)d_in[0];
    const float* votes    = (const float*)d_in[1];
    const float* scales   = (const float*)d_in[2];
    const float* vpp      = (const float*)d_in[3];
    const float* presence = (const float*)d_in[4];
    const int*   nv       = (const int*)d_in[5];
    float* out = (float*)d_out;
    float* ws  = (float*)d_ws;

    dim3 g(GRID_X, B);
    k_fused<<<g, 256, 0, stream>>>(x, votes, scales, vpp, presence, nv, out, ws);
    k_reduce<<<1, 256, 0, stream>>>(ws, out, GRID_X * B);
}